// Round 3
// baseline (54.918 us; speedup 1.0000x reference)
//
#include <hip/hip_runtime.h>

#define NPTS   384
#define DIM    256
#define SPLIT  4
#define JB     (NPTS/SPLIT)   // 96 negatives-slice per block
#define NBLK   (NPTS*SPLIT)   // 1536 blocks (exactly 6/CU, all co-resident)
#define MAXK   64             // cap on same-class count (expected ~12)
#define MARGIN 1.0f

__device__ __forceinline__ float wave_red_sum(float p) {
    #pragma unroll
    for (int m = 1; m < 64; m <<= 1) p += __shfl_xor(p, m, 64);
    return p;
}

// Fused: per-(anchor i, j-slice s) block computes partial num/cnt; the last
// block to finish (ticket) reduces all partials in fixed order -> out.
__global__ __launch_bounds__(256) void triplet_fused(const float* __restrict__ x,
                                                     const int* __restrict__ labels,
                                                     float2* __restrict__ partial,
                                                     unsigned int* __restrict__ ticket,
                                                     float* __restrict__ out) {
    const int i    = blockIdx.x;
    const int s    = blockIdx.y;
    const int tid  = threadIdx.x;
    const int lane = tid & 63;
    const int wid  = tid >> 6;

    __shared__ int   lab[NPTS];
    __shared__ int   kidx[MAXK];
    __shared__ float dk[MAXK];
    __shared__ float dj[JB];
    __shared__ int   nk_sh;
    __shared__ float wnum[4];
    __shared__ float wcnt[4];
    __shared__ int   last_sh;

    // anchor fragment: lane l holds x[i, 4l..4l+3] (whole row across one wave)
    const float4 bx = *(const float4*)(x + (size_t)i * DIM + lane * 4);

    if (wid == 0) {
        // wave 0: stage labels, ballot-compact positives, then positive-k dots
        #pragma unroll
        for (int c = 0; c < 6; ++c) lab[c * 64 + lane] = labels[c * 64 + lane];
        const int li = lab[i];
        int base = 0;
        #pragma unroll
        for (int c = 0; c < 6; ++c) {
            const bool m = (lab[c * 64 + lane] == li);
            const unsigned long long mk = __ballot(m);
            const int pre = __popcll(mk & ((1ull << lane) - 1ull));
            const int p = base + pre;
            if (m && p < MAXK) kidx[p] = c * 64 + lane;
            base += __popcll(mk);          // wave-uniform
        }
        const int nk = (base > MAXK) ? MAXK : base;
        if (lane == 0) nk_sh = nk;
        for (int t = 0; t < nk; ++t) {
            const int row = kidx[t];       // LDS broadcast
            const float4 a = *(const float4*)(x + (size_t)row * DIM + lane * 4);
            const float d0 = a.x - bx.x, d1 = a.y - bx.y,
                        d2 = a.z - bx.z, d3 = a.w - bx.w;
            const float p = wave_red_sum(d0*d0 + d1*d1 + d2*d2 + d3*d3);
            if (lane == 0) dk[t] = p;
        }
    } else {
        // waves 1-3: 32 negative-j dots each (fixed trip -> pipelined loads)
        const int j0 = s * JB + (wid - 1) * 32;
        #pragma unroll 8
        for (int u = 0; u < 32; ++u) {
            const float4 a = *(const float4*)(x + (size_t)(j0 + u) * DIM + lane * 4);
            const float d0 = a.x - bx.x, d1 = a.y - bx.y,
                        d2 = a.z - bx.z, d3 = a.w - bx.w;
            const float p = wave_red_sum(d0*d0 + d1*d1 + d2*d2 + d3*d3);
            if (lane == 0) dj[(wid - 1) * 32 + u] = p;
        }
    }
    __syncthreads();

    // hinge accumulation: thread tid<96 owns j = s*96+tid
    const int li = lab[i];
    const int nk = nk_sh;
    float num = 0.f, cnt = 0.f;
    if (tid < JB) {
        const int j = s * JB + tid;
        if (lab[j] != li) {
            const float b = dj[tid] - MARGIN;
            for (int t = 0; t < nk; ++t) {
                const float h = b + dk[t];
                num += (h > 0.f) ? h : 0.f;
            }
            cnt = (float)nk;
        }
    }
    if (wid < 2) {                         // values live only in tid<96
        num = wave_red_sum(num);
        cnt = wave_red_sum(cnt);
        if (lane == 0) { wnum[wid] = num; wcnt[wid] = cnt; }
    }
    __syncthreads();
    if (tid == 0) {
        float2 pr;
        pr.x = wnum[0] + wnum[1];
        pr.y = wcnt[0] + wcnt[1];
        partial[s * NPTS + i] = pr;
        __threadfence();                   // release partial before ticket
        const unsigned int old = atomicAdd(ticket, 1u);
        last_sh = (old == NBLK - 1) ? 1 : 0;
    }
    __syncthreads();

    if (last_sh) {                         // last block: deterministic final reduce
        __threadfence();                   // acquire: see all partials
        float n = 0.f, c = 0.f;
        for (int p = tid; p < NBLK; p += 256) {
            const float2 v = partial[p];
            n += v.x; c += v.y;
        }
        n = wave_red_sum(n);
        c = wave_red_sum(c);
        if (lane == 0) { wnum[wid] = n; wcnt[wid] = c; }
        __syncthreads();
        if (tid == 0)
            out[0] = (wnum[0] + wnum[1] + wnum[2] + wnum[3]) /
                     (wcnt[0] + wcnt[1] + wcnt[2] + wcnt[3]);
    }
}

extern "C" void kernel_launch(void* const* d_in, const int* in_sizes, int n_in,
                              void* d_out, int out_size, void* d_ws, size_t ws_size,
                              hipStream_t stream) {
    const float* x      = (const float*)d_in[0];
    const int*   labels = (const int*)d_in[1];
    float*       out    = (float*)d_out;

    float2*       partial = (float2*)d_ws;
    unsigned int* ticket  = (unsigned int*)((char*)d_ws + NBLK * sizeof(float2));

    hipMemsetAsync(ticket, 0, sizeof(unsigned int), stream);
    dim3 grid(NPTS, SPLIT);
    triplet_fused<<<grid, 256, 0, stream>>>(x, labels, partial, ticket, out);
}

// Round 4
// 19.155 us; speedup vs baseline: 2.8671x; 2.8671x over previous
//
#include <hip/hip_runtime.h>

#define NPTS   384
#define DIM    256
#define MAXK   64       // cap on same-class count (expected ~12)
#define MARGIN 1.0f

__device__ __forceinline__ float wave_red_sum(float p) {
    #pragma unroll
    for (int m = 1; m < 64; m <<= 1) p += __shfl_xor(p, m, 64);
    return p;
}

// One block per anchor i (384 blocks x 256 threads = 4 waves).
// Phase 1: all 4 waves compute the full d-row with quarter-wave dots
//          (16 lanes/row, 4 rows per group -> only 4 shfl + 1 LDS write per 4 rows).
// Phase 2: ballot-compact same-class k indices (wave 0, parallel, deterministic).
// Phase 3: hinge accumulation + block reduce -> partial[i] = {num, cnt}.
__global__ __launch_bounds__(256) void triplet_main(const float* __restrict__ x,
                                                    const int* __restrict__ labels,
                                                    float2* __restrict__ partial) {
    const int i    = blockIdx.x;
    const int tid  = threadIdx.x;
    const int lane = tid & 63;
    const int wid  = tid >> 6;
    const int sub  = lane >> 4;   // which of 4 rows in the group
    const int l16  = lane & 15;   // element-slice lane within the row

    __shared__ int   lab[NPTS];
    __shared__ float drow[NPTS];
    __shared__ int   kidx[MAXK];
    __shared__ int   nk_sh;
    __shared__ float wnum[4], wcnt[4];

    for (int j = tid; j < NPTS; j += 256) lab[j] = labels[j];

    // anchor fragment for this lane's element slice: elems l16*4 + q*64
    float4 bx[4];
    #pragma unroll
    for (int q = 0; q < 4; ++q)
        bx[q] = *(const float4*)(x + (size_t)i * DIM + l16 * 4 + q * 64);

    // quarter-wave dots: wave owns rows [wid*96, wid*96+96), 4 rows/iteration
    #pragma unroll 4
    for (int u = 0; u < 24; ++u) {
        const int r = wid * 96 + u * 4 + sub;
        const float* xr = x + (size_t)r * DIM + l16 * 4;
        float acc = 0.f;
        #pragma unroll
        for (int q = 0; q < 4; ++q) {
            const float4 a = *(const float4*)(xr + q * 64);
            const float d0 = a.x - bx[q].x, d1 = a.y - bx[q].y,
                        d2 = a.z - bx[q].z, d3 = a.w - bx[q].w;
            acc += d0*d0 + d1*d1 + d2*d2 + d3*d3;
        }
        #pragma unroll
        for (int m = 1; m < 16; m <<= 1) acc += __shfl_xor(acc, m, 64);
        if (l16 == 0) drow[r] = acc;
    }
    __syncthreads();

    const int li = lab[i];

    // ballot compaction of same-class k indices (wave 0 only; ~6 steps)
    if (wid == 0) {
        int base = 0;
        #pragma unroll
        for (int c = 0; c < 6; ++c) {
            const bool m = (lab[c * 64 + lane] == li);
            const unsigned long long mk = __ballot(m);
            const int pre = __popcll(mk & ((1ull << lane) - 1ull));
            const int p = base + pre;
            if (m && p < MAXK) kidx[p] = c * 64 + lane;
            base += __popcll(mk);          // wave-uniform
        }
        if (lane == 0) nk_sh = (base > MAXK) ? MAXK : base;
    }
    __syncthreads();
    const int nk = nk_sh;

    // hinge accumulation: each thread owns j = tid and j = tid+256
    float num = 0.f, cnt = 0.f;
    for (int j = tid; j < NPTS; j += 256) {
        if (lab[j] != li) {
            const float b = drow[j] - MARGIN;
            for (int t = 0; t < nk; ++t) {
                const float h = b + drow[kidx[t]];   // wave-uniform LDS broadcasts
                num += (h > 0.f) ? h : 0.f;
            }
            cnt += (float)nk;
        }
    }
    num = wave_red_sum(num);
    cnt = wave_red_sum(cnt);
    if (lane == 0) { wnum[wid] = num; wcnt[wid] = cnt; }
    __syncthreads();
    if (tid == 0)
        partial[i] = make_float2(wnum[0] + wnum[1] + wnum[2] + wnum[3],
                                 wcnt[0] + wcnt[1] + wcnt[2] + wcnt[3]);
}

__global__ __launch_bounds__(256) void triplet_finalize(const float2* __restrict__ partial,
                                                        float* __restrict__ out) {
    const int tid = threadIdx.x, lane = tid & 63, wid = tid >> 6;
    __shared__ float wnum[4], wcnt[4];
    float n = 0.f, c = 0.f;
    for (int p = tid; p < NPTS; p += 256) {
        const float2 v = partial[p];
        n += v.x; c += v.y;
    }
    n = wave_red_sum(n);
    c = wave_red_sum(c);
    if (lane == 0) { wnum[wid] = n; wcnt[wid] = c; }
    __syncthreads();
    if (tid == 0)
        out[0] = (wnum[0] + wnum[1] + wnum[2] + wnum[3]) /
                 (wcnt[0] + wcnt[1] + wcnt[2] + wcnt[3]);
}

extern "C" void kernel_launch(void* const* d_in, const int* in_sizes, int n_in,
                              void* d_out, int out_size, void* d_ws, size_t ws_size,
                              hipStream_t stream) {
    const float* x      = (const float*)d_in[0];
    const int*   labels = (const int*)d_in[1];
    float*       out    = (float*)d_out;

    float2* partial = (float2*)d_ws;

    triplet_main<<<NPTS, 256, 0, stream>>>(x, labels, partial);
    triplet_finalize<<<1, 256, 0, stream>>>(partial, out);
}